// Round 5
// baseline (152.200 us; speedup 1.0000x reference)
//
#include <hip/hip_runtime.h>

typedef float v2f __attribute__((ext_vector_type(2)));
typedef float v4f __attribute__((ext_vector_type(4)));

#define IMG_H 1080
#define IMG_W 1920
#define NBATCH 8
#define NI 2                 // images per wave (dual-stream ILP)
#define LSTRIP 9             // output rows per lane
#define BROWS (4*LSTRIP)     // 36 rows per block
#define NK (LSTRIP+4)        // 13 schedule rows
#define PF 4                 // prefetch distance (rows ahead)
#define RS 5                 // raw-row ring slots (PF+1)

// R13: "dual-stream ILP" — R8 (13 loads in flight), R11 (2x grid), R12
// (30 waves/CU resident by construction) ALL landed at 41-47us with
// VALUBusy ~46-49%. Residency and per-wave memory depth are both
// exonerated; the invariant is ONE serial chain per wave
// (vmem -> bperm(DS ~120cy) -> partials -> products) so all waves stall
// in the same places and the SIMD idles ~52%. Fix: each wave processes
// TWO images (z and z+4) at identical coordinates — two fully
// independent dependency chains interleaved by the scheduler; stream B's
// VALU fills stream A's bperm/load shadows. Addressing/clamps/bperm
// addresses shared; registers ~2x (est ~100 < 128 -> 4 waves/SIMD).
// launch_bounds(256,3): budget ~170, spill-safe (R9/R11 precedent).
// Edge algebra per-image identical to validated R7-R12.

static __device__ __forceinline__ v2f vfma2(v2f a, v2f b, v2f c) {
    return __builtin_elementwise_fma(a, b, c);
}
static __device__ __forceinline__ float bperm(int addr, float v) {
    return __int_as_float(__builtin_amdgcn_ds_bpermute(addr, __float_as_int(v)));
}

__global__ __launch_bounds__(256, 3)
void shi_tomasi_kernel(const float* __restrict__ img, float* __restrict__ out) {
    const int cg    = threadIdx.x & 63;            // lane within wave
    const int strip = threadIdx.x >> 6;            // wave-uniform 0..3
    const int bx    = blockIdx.x;
    const int base  = bx * 240;
    const int cl    = min(max(base - 8 + 4 * cg, 0), IMG_W - 4);  // load col
    const int c0    = base + 4 * (cg - 2);         // output col (lanes 2..61)
    const int s0    = blockIdx.y * BROWS + strip * LSTRIP;
    const size_t HW = (size_t)IMG_H * IMG_W;
    const float* g0 = img + (size_t)blockIdx.z * HW;        // image z
    const float* g1 = g0 + 4 * HW;                          // image z+4
    float* ob0      = out + (size_t)blockIdx.z * HW;
    float* ob1      = ob0 + 4 * HW;

    const bool eL     = (bx == 0) && (cg == 2);    // c0 == 0
    const bool eR     = (bx == 7) && (cg == 61);   // c0 == W-4
    const bool doSt   = (cg >= 2) && (cg < 62);
    const int  aLft   = 4 * (cg - 1);
    const int  aRgt   = 4 * (cg + 1);
    const bool topFix = (s0 == 0);                 // wave-uniform
    const bool botFix = (s0 + LSTRIP == IMG_H);    // wave-uniform

    const float* lp0 = g0 + cl;
    const float* lp1 = g1 + cl;

    // ---- preload first PF raw rows into both rings ----
    v4f Zr[NI][RS];
    #pragma unroll
    for (int k = 0; k < PF; ++k) {
        int lr = s0 - 2 + k;                       // wave-uniform -> scalar
        lr = max(0, min(IMG_H - 1, lr));
        Zr[0][k % RS] = *(const v4f*)(lp0 + (size_t)lr * IMG_W);
        Zr[1][k % RS] = *(const v4f*)(lp1 + (size_t)lr * IMG_W);
    }

    v2f hdR[NI][3][3], hsR[NI][3][3];
    float hfd[NI][3], hfs[NI][3];
    v2f hxx[NI][3][2], hyy[NI][3][2], hxy[NI][3][2];
    const v2f two = {2.0f, 2.0f};

    #pragma unroll
    for (int k = 0; k < NK; ++k) {
        // ---- rolling prefetch: issue loads for row k+PF (both streams) ----
        if (k + PF < NK) {
            int lr = s0 - 2 + k + PF;              // wave-uniform -> scalar
            lr = max(0, min(IMG_H - 1, lr));
            Zr[0][(k + PF) % RS] = *(const v4f*)(lp0 + (size_t)lr * IMG_W);
            Zr[1][(k + PF) % RS] = *(const v4f*)(lp1 + (size_t)lr * IMG_W);
        }

        // ---- separable partials for schedule row k, both streams ----
        #pragma unroll
        for (int im = 0; im < NI; ++im) {
            const v4f Z = Zr[im][k % RS];
            const float zl0 = bperm(aLft, Z.z), zl1 = bperm(aLft, Z.w);
            const float zr0 = bperm(aRgt, Z.x), zr1 = bperm(aRgt, Z.y);
            v2f Z0 = v2f{zl0, zl1};
            if (eL) Z0 = v2f{Z.x, Z.x};            // replicate col 0
            const v2f Z1 = v2f{Z.x, Z.y};
            const v2f Z2 = v2f{Z.z, Z.w};
            v2f Z3 = v2f{zr0, zr1};
            if (eR) Z3 = v2f{Z.w, Z.w};            // replicate col W-1

            const v2f Sab = v2f{Z0.y, Z1.x};
            const v2f Sbc = v2f{Z1.y, Z2.x};
            const v2f Scd = v2f{Z2.y, Z3.x};
            v2f* hd = hdR[im][k % 3];
            v2f* hs = hsR[im][k % 3];
            hd[0] = Z1 - Z0; hd[1] = Z2 - Z1; hd[2] = Z3 - Z2;
            hs[0] = vfma2(Sab, two, Z0) + Z1;
            hs[1] = vfma2(Sbc, two, Z1) + Z2;
            hs[2] = vfma2(Scd, two, Z2) + Z3;
            // double-clamped edge-col partials (virtual col -1 / col W)
            hfd[im][k % 3] = eR ? (Z2.y - Z2.x) : (Z1.y - Z1.x);
            hfs[im][k % 3] = eR ? (Z2.x + 3.0f * Z2.y) : (3.0f * Z1.x + Z1.y);
        }

        // ---- product row vr = s0-1+(k-2) (k>=2), both streams ----
        if (k >= 2) {
            const int rr = k - 2;
            const int sm = rr % 3, sz = (rr + 1) % 3, sp = (rr + 2) % 3;

            #pragma unroll
            for (int im = 0; im < NI; ++im) {
                v2f Ixp[3], Iyp[3];
                #pragma unroll
                for (int j = 0; j < 3; ++j) {
                    Ixp[j] = vfma2(hdR[im][sz][j], two, hdR[im][sm][j]) + hdR[im][sp][j];
                    Iyp[j] = hsR[im][sp][j] - hsR[im][sm][j];
                }
                const float ixf = hfd[im][sm] + 2.0f * hfd[im][sz] + hfd[im][sp];
                const float iyf = hfs[im][sp] - hfs[im][sm];
                if (eL) { Ixp[0].x = ixf; Iyp[0].x = iyf; }
                if (eR) { Ixp[2].y = ixf; Iyp[2].y = iyf; }

                v2f xx[3], yy[3], xy[3];
                #pragma unroll
                for (int j = 0; j < 3; ++j) {
                    xx[j] = Ixp[j] * Ixp[j];
                    yy[j] = Iyp[j] * Iyp[j];
                    xy[j] = Ixp[j] * Iyp[j];
                }
                {
                    v2f* hx = hxx[im][rr % 3];
                    v2f* hy = hyy[im][rr % 3];
                    v2f* hz = hxy[im][rr % 3];
                    hx[0] = xx[0] + v2f{xx[0].y, xx[1].x} + xx[1];
                    hx[1] = xx[1] + v2f{xx[1].y, xx[2].x} + xx[2];
                    hy[0] = yy[0] + v2f{yy[0].y, yy[1].x} + yy[1];
                    hy[1] = yy[1] + v2f{yy[1].y, yy[2].x} + yy[2];
                    hz[0] = xy[0] + v2f{xy[0].y, xy[1].x} + xy[1];
                    hz[1] = xy[1] + v2f{xy[1].y, xy[2].x} + xy[2];
                }
                if (rr == 1 && topFix) {               // P(-1) == P(0)
                    #pragma unroll
                    for (int q = 0; q < 2; ++q) {
                        hxx[im][0][q] = hxx[im][1][q];
                        hyy[im][0][q] = hyy[im][1][q];
                        hxy[im][0][q] = hxy[im][1][q];
                    }
                }
                if (rr == LSTRIP + 1 && botFix) {      // P(H) == P(H-1)
                    #pragma unroll
                    for (int q = 0; q < 2; ++q) {
                        hxx[im][rr % 3][q] = hxx[im][(rr - 1) % 3][q];
                        hyy[im][rr % 3][q] = hyy[im][(rr - 1) % 3][q];
                        hxy[im][rr % 3][q] = hxy[im][(rr - 1) % 3][q];
                    }
                }

                if (rr >= 2) {
                    const int a = (rr - 2) % 3, b2 = (rr - 1) % 3, c = rr % 3;
                    float rv[4];
                    #pragma unroll
                    for (int q = 0; q < 2; ++q) {
                        const v2f sxx = hxx[im][a][q] + hxx[im][b2][q] + hxx[im][c][q];
                        const v2f syy = hyy[im][a][q] + hyy[im][b2][q] + hyy[im][c][q];
                        const v2f sxy = hxy[im][a][q] + hxy[im][b2][q] + hxy[im][c][q];
                        const v2f S = sxx + syy;
                        const v2f D = sxx - syy;
                        const v2f E = sxy + sxy;
                        const v2f disc = vfma2(D, D, vfma2(E, E, v2f{4e-10f, 4e-10f}));
                        const v2f qv = {__builtin_sqrtf(disc.x), __builtin_sqrtf(disc.y)};
                        const v2f lam = (S - qv) * 0.5f;
                        rv[2 * q]     = fmaxf(lam.x, 0.0f);
                        rv[2 * q + 1] = fmaxf(lam.y, 0.0f);
                    }
                    if (doSt) {
                        float* orowp = (im == 0 ? ob0 : ob1)
                                     + (size_t)(s0 + rr - 2) * IMG_W + c0;
                        __builtin_nontemporal_store(v4f{rv[0], rv[1], rv[2], rv[3]},
                                                    (v4f*)orowp);
                    }
                }
            }
        }
    }
}

extern "C" void kernel_launch(void* const* d_in, const int* in_sizes, int n_in,
                              void* d_out, int out_size, void* d_ws, size_t ws_size,
                              hipStream_t stream) {
    const float* img = (const float*)d_in[0];
    float* out = (float*)d_out;
    dim3 grid(8, IMG_H / BROWS, NBATCH / NI);      // 8 x 30 x 4 = 960 blocks
    shi_tomasi_kernel<<<grid, 256, 0, stream>>>(img, out);
}

// Round 6
// 117.645 us; speedup vs baseline: 1.2937x; 1.2937x over previous
//
#include <hip/hip_runtime.h>

typedef float v2f __attribute__((ext_vector_type(2)));
typedef float v4f __attribute__((ext_vector_type(4)));

#define IMG_H 1080
#define IMG_W 1920
#define NBATCH 8
#define LSTRIP 9             // output rows per lane
#define BROWS (4*LSTRIP)     // 36 rows per block
#define NK (LSTRIP+4)        // 13 schedule rows
#define PF 4                 // prefetch distance (rows ahead)
#define ZS 6                 // raw ring slots (= body period)

// R14: "loopify — attack instruction footprint". R8 (mem depth), R11
// (grid), R12 (30 waves/CU by construction), R13 (dual-chain ILP) ALL
// left VALUBusy pinned at ~48% / 42-44us. The untested invariant: every
// version is a fully-unrolled 13-row straight-line body (~20KB text,
// zero instruction reuse per wave) -> instruction-fetch streaming caps
// issue at ~1/2cyc; extra waves sit at scattered PCs and make fetch
// WORSE (explains R12 null; R9's 2x body was 17% worse per work; R13's
// 2x body collapsed). Fix: 6-row rotating body in a REAL loop (trip 2,
// unroll disabled) + 1-row epilogue. All ring indices compile-time per
// body position (no scratch, rule #20); row numbers/pointers runtime
// scalar; edge fixes are wave-uniform branches at fixed positions.
// Text ~20KB -> ~12KB, all waves loop in the same hot region.
// Edge algebra identical to validated R7-R13 (single-stream form).

static __device__ __forceinline__ v2f vfma2(v2f a, v2f b, v2f c) {
    return __builtin_elementwise_fma(a, b, c);
}
static __device__ __forceinline__ float bperm(int addr, float v) {
    return __int_as_float(__builtin_amdgcn_ds_bpermute(addr, __float_as_int(v)));
}

__global__ __launch_bounds__(256, 3)
void shi_tomasi_kernel(const float* __restrict__ img, float* __restrict__ out) {
    const int cg    = threadIdx.x & 63;            // lane within wave
    const int strip = threadIdx.x >> 6;            // wave-uniform 0..3
    const int bx    = blockIdx.x;
    const int base  = bx * 240;
    const int cl    = min(max(base - 8 + 4 * cg, 0), IMG_W - 4);  // load col
    const int c0    = base + 4 * (cg - 2);         // output col (lanes 2..61)
    const int s0    = blockIdx.y * BROWS + strip * LSTRIP;
    const float* g  = img + (size_t)blockIdx.z * (IMG_H * IMG_W);
    float* outb     = out + (size_t)blockIdx.z * (IMG_H * IMG_W);

    const bool eL     = (bx == 0) && (cg == 2);    // c0 == 0
    const bool eR     = (bx == 7) && (cg == 61);   // c0 == W-4
    const bool doSt   = (cg >= 2) && (cg < 62);
    const int  aLft   = 4 * (cg - 1);
    const int  aRgt   = 4 * (cg + 1);
    const bool topFix = (s0 == 0);                 // wave-uniform
    const bool botFix = (s0 + LSTRIP == IMG_H);    // wave-uniform

    const float* lp = g + cl;

    // ---- prologue: rows 0..PF-1 into ring phases 0..3 ----
    v4f Zr[ZS];
    #pragma unroll
    for (int k = 0; k < PF; ++k) {
        int lr = max(0, min(IMG_H - 1, s0 - 2 + k));
        Zr[k] = *(const v4f*)(lp + (size_t)lr * IMG_W);
    }

    v2f hdR[3][3], hsR[3][3];
    float hfd[3], hfs[3];
    v2f hxx[3][2], hyy[3][2], hxy[3][2];
    const v2f two = {2.0f, 2.0f};

// One schedule row at body position J (k == J mod 6). All ring indices
// compile-time; kk/pointers runtime scalar. Phase map (k == J mod 6):
//   Zr consume = J, Zr prefetch-write = (J+PF)%6
//   hd/hs write & product "sp" (newest) = J%3
//   product "sm" (oldest) & hxx write (rr%3) = (J+1)%3
//   product "sz" (middle) & store "a" = (J+2)%3
#define ROW_BODY(J, kk, doPre, doProd, doStore, doTFix, doBFix) do {         \
    constexpr int ZP = (J) % ZS, ZQ = ((J) + PF) % ZS;                       \
    constexpr int P0 = (J) % 3, P1 = ((J) + 1) % 3, P2 = ((J) + 2) % 3;      \
    if (doPre) {                                                             \
        int lr = min(IMG_H - 1, s0 + (kk) + 2);     /* s0-2+kk+PF */         \
        Zr[ZQ] = *(const v4f*)(lp + (size_t)lr * IMG_W);                     \
    }                                                                        \
    {                                                                        \
        const v4f Z = Zr[ZP];                                                \
        const float zl0 = bperm(aLft, Z.z), zl1 = bperm(aLft, Z.w);          \
        const float zr0 = bperm(aRgt, Z.x), zr1 = bperm(aRgt, Z.y);          \
        v2f Z0 = v2f{zl0, zl1};                                              \
        if (eL) Z0 = v2f{Z.x, Z.x};                 /* replicate col 0 */    \
        const v2f Z1 = v2f{Z.x, Z.y};                                        \
        const v2f Z2 = v2f{Z.z, Z.w};                                        \
        v2f Z3 = v2f{zr0, zr1};                                              \
        if (eR) Z3 = v2f{Z.w, Z.w};                 /* replicate col W-1 */  \
        const v2f Sab = v2f{Z0.y, Z1.x};                                     \
        const v2f Sbc = v2f{Z1.y, Z2.x};                                     \
        const v2f Scd = v2f{Z2.y, Z3.x};                                     \
        hdR[P0][0] = Z1 - Z0; hdR[P0][1] = Z2 - Z1; hdR[P0][2] = Z3 - Z2;    \
        hsR[P0][0] = vfma2(Sab, two, Z0) + Z1;                               \
        hsR[P0][1] = vfma2(Sbc, two, Z1) + Z2;                               \
        hsR[P0][2] = vfma2(Scd, two, Z2) + Z3;                               \
        hfd[P0] = eR ? (Z2.y - Z2.x) : (Z1.y - Z1.x);                        \
        hfs[P0] = eR ? (Z2.x + 3.0f * Z2.y) : (3.0f * Z1.x + Z1.y);          \
    }                                                                        \
    if (doProd) {                                                            \
        v2f Ixp[3], Iyp[3];                                                  \
        _Pragma("unroll")                                                    \
        for (int j = 0; j < 3; ++j) {                                        \
            Ixp[j] = vfma2(hdR[P2][j], two, hdR[P1][j]) + hdR[P0][j];        \
            Iyp[j] = hsR[P0][j] - hsR[P1][j];                                \
        }                                                                    \
        const float ixf = hfd[P1] + 2.0f * hfd[P2] + hfd[P0];                \
        const float iyf = hfs[P0] - hfs[P1];                                 \
        if (eL) { Ixp[0].x = ixf; Iyp[0].x = iyf; }                          \
        if (eR) { Ixp[2].y = ixf; Iyp[2].y = iyf; }                          \
        v2f xx[3], yy[3], xy[3];                                             \
        _Pragma("unroll")                                                    \
        for (int j = 0; j < 3; ++j) {                                        \
            xx[j] = Ixp[j] * Ixp[j];                                         \
            yy[j] = Iyp[j] * Iyp[j];                                         \
            xy[j] = Ixp[j] * Iyp[j];                                         \
        }                                                                    \
        hxx[P1][0] = xx[0] + v2f{xx[0].y, xx[1].x} + xx[1];                  \
        hxx[P1][1] = xx[1] + v2f{xx[1].y, xx[2].x} + xx[2];                  \
        hyy[P1][0] = yy[0] + v2f{yy[0].y, yy[1].x} + yy[1];                  \
        hyy[P1][1] = yy[1] + v2f{yy[1].y, yy[2].x} + yy[2];                  \
        hxy[P1][0] = xy[0] + v2f{xy[0].y, xy[1].x} + xy[1];                  \
        hxy[P1][1] = xy[1] + v2f{xy[1].y, xy[2].x} + xy[2];                  \
        if ((doTFix) && topFix) {                   /* P(-1) == P(0) */      \
            _Pragma("unroll")                                                \
            for (int q = 0; q < 2; ++q) {                                    \
                hxx[P0][q] = hxx[P1][q];                                     \
                hyy[P0][q] = hyy[P1][q];                                     \
                hxy[P0][q] = hxy[P1][q];                                     \
            }                                                                \
        }                                                                    \
        if ((doBFix) && botFix) {                   /* P(H) == P(H-1) */     \
            _Pragma("unroll")                                                \
            for (int q = 0; q < 2; ++q) {                                    \
                hxx[P1][q] = hxx[P0][q];                                     \
                hyy[P1][q] = hyy[P0][q];                                     \
                hxy[P1][q] = hxy[P0][q];                                     \
            }                                                                \
        }                                                                    \
        if (doStore) {                                                       \
            float rv[4];                                                     \
            _Pragma("unroll")                                                \
            for (int q = 0; q < 2; ++q) {                                    \
                const v2f sxx = hxx[P2][q] + hxx[P0][q] + hxx[P1][q];        \
                const v2f syy = hyy[P2][q] + hyy[P0][q] + hyy[P1][q];        \
                const v2f sxy = hxy[P2][q] + hxy[P0][q] + hxy[P1][q];        \
                const v2f S = sxx + syy;                                     \
                const v2f D = sxx - syy;                                     \
                const v2f E = sxy + sxy;                                     \
                const v2f disc = vfma2(D, D, vfma2(E, E, v2f{4e-10f, 4e-10f})); \
                const v2f qv = {__builtin_sqrtf(disc.x), __builtin_sqrtf(disc.y)}; \
                const v2f lam = (S - qv) * 0.5f;                             \
                rv[2 * q]     = fmaxf(lam.x, 0.0f);                          \
                rv[2 * q + 1] = fmaxf(lam.y, 0.0f);                          \
            }                                                                \
            if (doSt) {                                                      \
                float* orowp = outb + (size_t)(s0 + (kk) - 4) * IMG_W + c0;  \
                __builtin_nontemporal_store(v4f{rv[0], rv[1], rv[2], rv[3]}, \
                                            (v4f*)orowp);                    \
            }                                                                \
        }                                                                    \
    }                                                                        \
} while (0)

    // ---- main loop: 2 iterations x 6 rows (k = 0..11), then k = 12 ----
    int k = 0;
    #pragma clang loop unroll(disable)
    for (int it = 0; it < 2; ++it) {
        const bool w = (it != 0);                  // k>=2 / k>=4 guards
        const bool f = (it == 0);                  // prefetch tail / topFix
        ROW_BODY(0, k, true,  w,    w,    false, false); ++k;
        ROW_BODY(1, k, true,  w,    w,    false, false); ++k;
        ROW_BODY(2, k, true,  true, w,    false, false); ++k;
        ROW_BODY(3, k, f,     true, w,    f,     false); ++k;
        ROW_BODY(4, k, f,     true, true, false, false); ++k;
        ROW_BODY(5, k, f,     true, true, false, false); ++k;
    }
    // epilogue: k = 12 (phase J=0; rr = 10 = LSTRIP+1 -> botFix here)
    ROW_BODY(0, k, false, true, true, false, true);

#undef ROW_BODY
}

extern "C" void kernel_launch(void* const* d_in, const int* in_sizes, int n_in,
                              void* d_out, int out_size, void* d_ws, size_t ws_size,
                              hipStream_t stream) {
    const float* img = (const float*)d_in[0];
    float* out = (float*)d_out;
    dim3 grid(8, IMG_H / BROWS, NBATCH);           // 8 x 30 x 8 = 1920 blocks
    shi_tomasi_kernel<<<grid, 256, 0, stream>>>(img, out);
}

// Round 8
// 117.325 us; speedup vs baseline: 1.2972x; 1.0027x over previous
//
#include <hip/hip_runtime.h>

typedef float v4f __attribute__((ext_vector_type(4)));

#define IMG_H 1080
#define IMG_W 1920
#define NBATCH 8
#define LSTRIP 9             // output rows per lane
#define BROWS (4*LSTRIP)     // 36 rows per block
#define NK (LSTRIP+4)        // 13 schedule rows
#define PF 3                 // prefetch distance (rows ahead)
#define RS 4                 // raw-row ring slots (PF+1)

// R16: "scalar window, no bperm" — R15's inline-asm pk ops broke
// correctness (unverifiable VOP3P semantics; abandoned). The measured
// 254 VALU instr/row vs ~175 needed comes from: 4 bperm/row + lgkm wait
// on the critical path, ~18 cross-half v2f shuffle movs/row, hfd/hfs
// virtual-col algebra. Fix in plain C++: each lane loads its own halo
// via TWO overlapping dwordx4 ([c-2,c+2) + [c+2,c+6)), window held as
// named scalars (shifts = free renaming), edges via 6 window selects +
// 4 field-replication selects — derived to be semantically identical
// to validated R7-R14 (eL: z-1:=z0, then Ix(-1):=Ix(0), Iy(-1):=Iy(0);
// eR mirrored). Zero LDS ops. launch_bounds(256,2): VGPR ceiling 256,
// no spill possible at ~180 regs (R10/R13 lesson). Occupancy 2/SIMD is
// established-sufficient (R12 null: extra waves never helped).

__global__ __launch_bounds__(256, 2)
void shi_tomasi_kernel(const float* __restrict__ img, float* __restrict__ out) {
    const int cg    = threadIdx.x & 63;            // lane within wave
    const int strip = threadIdx.x >> 6;            // wave-uniform 0..3
    const int bx    = blockIdx.x;
    const int base  = bx * 240;
    const int c0    = base + 4 * (cg - 2);         // output col (lanes 2..61)
    const int clA   = min(max(c0 - 2, 0), IMG_W - 4);  // left-halo load col
    const int clB   = min(max(c0 + 2, 0), IMG_W - 4);  // right-halo load col
    const int s0    = blockIdx.y * BROWS + strip * LSTRIP;
    const float* g  = img + (size_t)blockIdx.z * (IMG_H * IMG_W);
    float* outb     = out + (size_t)blockIdx.z * (IMG_H * IMG_W);

    const bool eL     = (bx == 0) && (cg == 2);    // c0 == 0
    const bool eR     = (bx == 7) && (cg == 61);   // c0 == W-4
    const bool doSt   = (cg >= 2) && (cg < 62);
    const bool topFix = (s0 == 0);                 // wave-uniform
    const bool botFix = (s0 + LSTRIP == IMG_H);    // wave-uniform

    const float* lpA = g + clA;
    const float* lpB = g + clB;

    // ---- prologue: rows s0-2 .. s0 into ring slots 0..PF-1 ----
    v4f za[RS], zb[RS];
    #pragma unroll
    for (int k = 0; k < PF; ++k) {
        int lr = max(0, min(IMG_H - 1, s0 - 2 + k));
        za[k] = *(const v4f*)(lpA + (size_t)lr * IMG_W);
        zb[k] = *(const v4f*)(lpB + (size_t)lr * IMG_W);
    }

    float cdR[3][6], hsR[3][6];                    // col-diff / col-smooth rings
    float hxx[3][4], hyy[3][4], hxy[3][4];         // horiz box-sum rings

    #pragma unroll
    for (int k = 0; k < NK; ++k) {
        // ---- rolling prefetch: row k+PF (lr = s0-2+k+PF >= 1, no max) ----
        if (k + PF < NK) {
            int lr = min(IMG_H - 1, s0 + k + (PF - 2));
            za[(k + PF) % RS] = *(const v4f*)(lpA + (size_t)lr * IMG_W);
            zb[(k + PF) % RS] = *(const v4f*)(lpB + (size_t)lr * IMG_W);
        }

        // ---- 8-px scalar window with edge replication ----
        {
            const v4f A = za[k % RS];              // interior: z[-2..1]
            const v4f B = zb[k % RS];              // interior: z[2..5]
            // eL lane: A = img[0..4) -> replicate col 0 (z-2=z-1=z0)
            // eR lane: B = img[W-4..W) -> replicate col W-1 (z4=z5=z3)
            const float zm2 = A.x;                 // eL: A.x == z0 (free)
            const float zm1 = eL ? A.x : A.y;
            const float z0  = eL ? A.x : A.z;
            const float z1  = eL ? A.y : A.w;
            const float z2  = eR ? B.z : B.x;
            const float z3  = eR ? B.w : B.y;
            const float z4  = eR ? B.w : B.z;
            const float z5  = B.w;                 // eR: B.w == z3-rep (free)

            float* cdw = cdR[k % 3];
            float* hsw = hsR[k % 3];
            cdw[0] = z0 - zm2;                     // coldiff at p = -1..4
            cdw[1] = z1 - zm1;
            cdw[2] = z2 - z0;
            cdw[3] = z3 - z1;
            cdw[4] = z4 - z2;
            cdw[5] = z5 - z3;
            hsw[0] = fmaf(2.0f, zm1, zm2) + z0;    // colsmooth at p = -1..4
            hsw[1] = fmaf(2.0f, z0, zm1) + z1;
            hsw[2] = fmaf(2.0f, z1, z0) + z2;
            hsw[3] = fmaf(2.0f, z2, z1) + z3;
            hsw[4] = fmaf(2.0f, z3, z2) + z4;
            hsw[5] = fmaf(2.0f, z4, z3) + z5;
        }

        // ---- product row vr = s0-1+(k-2) (k>=2) ----
        if (k >= 2) {
            const int rr = k - 2;
            const int sm = rr % 3, sz = (rr + 1) % 3, sp = (rr + 2) % 3;

            float Ix[6], Iy[6];
            #pragma unroll
            for (int p = 0; p < 6; ++p) {
                Ix[p] = fmaf(2.0f, cdR[sz][p], cdR[sm][p]) + cdR[sp][p];
                Iy[p] = hsR[sp][p] - hsR[sm][p];
            }
            // field replication at image borders (== validated hfd/hfs path)
            if (eL) { Ix[0] = Ix[1]; Iy[0] = Iy[1]; }
            if (eR) { Ix[5] = Ix[4]; Iy[5] = Iy[4]; }

            float xx[6], yy[6], xy[6];
            #pragma unroll
            for (int p = 0; p < 6; ++p) {
                xx[p] = Ix[p] * Ix[p];
                yy[p] = Iy[p] * Iy[p];
                xy[p] = Ix[p] * Iy[p];
            }
            {
                float* hx = hxx[rr % 3];
                float* hy = hyy[rr % 3];
                float* hz = hxy[rr % 3];
                #pragma unroll
                for (int c = 0; c < 4; ++c) {
                    hx[c] = (xx[c] + xx[c + 1]) + xx[c + 2];
                    hy[c] = (yy[c] + yy[c + 1]) + yy[c + 2];
                    hz[c] = (xy[c] + xy[c + 1]) + xy[c + 2];
                }
            }
            if (rr == 1 && topFix) {               // P(-1) == P(0)
                #pragma unroll
                for (int c = 0; c < 4; ++c) {
                    hxx[0][c] = hxx[1][c]; hyy[0][c] = hyy[1][c]; hxy[0][c] = hxy[1][c];
                }
            }
            if (rr == LSTRIP + 1 && botFix) {      // P(H) == P(H-1)
                #pragma unroll
                for (int c = 0; c < 4; ++c) {
                    hxx[rr % 3][c] = hxx[(rr - 1) % 3][c];
                    hyy[rr % 3][c] = hyy[(rr - 1) % 3][c];
                    hxy[rr % 3][c] = hxy[(rr - 1) % 3][c];
                }
            }

            if (rr >= 2) {
                const int a = (rr - 2) % 3, b2 = (rr - 1) % 3, cc = rr % 3;
                float rv[4];
                #pragma unroll
                for (int c = 0; c < 4; ++c) {
                    const float sxx = (hxx[a][c] + hxx[b2][c]) + hxx[cc][c];
                    const float syy = (hyy[a][c] + hyy[b2][c]) + hyy[cc][c];
                    const float sxy = (hxy[a][c] + hxy[b2][c]) + hxy[cc][c];
                    const float S = sxx + syy;
                    const float D = sxx - syy;
                    const float E = sxy + sxy;
                    const float disc = fmaf(D, D, fmaf(E, E, 4e-10f));
                    const float q = __builtin_sqrtf(disc);
                    rv[c] = fmaxf((S - q) * 0.5f, 0.0f);
                }
                if (doSt) {
                    float* orowp = outb + (size_t)(s0 + rr - 2) * IMG_W + c0;
                    __builtin_nontemporal_store(v4f{rv[0], rv[1], rv[2], rv[3]},
                                                (v4f*)orowp);
                }
            }
        }
    }
}

extern "C" void kernel_launch(void* const* d_in, const int* in_sizes, int n_in,
                              void* d_out, int out_size, void* d_ws, size_t ws_size,
                              hipStream_t stream) {
    const float* img = (const float*)d_in[0];
    float* out = (float*)d_out;
    dim3 grid(8, IMG_H / BROWS, NBATCH);           // 8 x 30 x 8 = 1920 blocks
    shi_tomasi_kernel<<<grid, 256, 0, stream>>>(img, out);
}